// Round 3
// baseline (13.418 us; speedup 1.0000x reference)
//
#include <hip/hip_runtime.h>

// out[b,n,k] = |scale| * sum_d (table[d,k] - x[b,n,d])^2
//            = |scale| * ( T2[k] + X2[row] - 2 * dot(x_row, t_k) )
// B=4, N=2048, D=64, K=256, fp32.
//
// R3: same per-wave structure as R2 (wave covers all 256 k via float4,
// 4 rows/wave), but 4 waves fused per block -> 512 blocks of 256 threads.
// Floor-discrimination round: if dur_us is unchanged, measurement is
// launch-overhead-dominated (kernel-proper ~2.5-3.5us vs ~10us overhead).

#define TD_D  64
#define TD_K  256
#define TD_RW 4          // rows per wave
#define TD_W  4          // waves per block

typedef float f4 __attribute__((ext_vector_type(4)));

__global__ __launch_bounds__(256)
void TableDistance_5669356831001_kernel(
    const float* __restrict__ x,      // [8192, 64]
    const float* __restrict__ table,  // [64, 256]
    const float* __restrict__ scale,  // [1]
    float* __restrict__ out)          // [8192, 256]
{
    const int tid  = threadIdx.x;
    const int wave = tid >> 6;               // 0..3
    const int lane = tid & 63;               // 0..63
    const int row0 = blockIdx.x * (TD_RW * TD_W) + wave * TD_RW;

    __shared__ f4 xs[TD_W][TD_RW][TD_D / 4]; // 4 KB

    // Stage this wave's 4 rows: lane l -> row (l>>4), d-chunk (l&15).
    const int sr = lane >> 4, sc = lane & 15;
    f4 xv = *(const f4*)&x[(size_t)(row0 + sr) * TD_D + sc * 4];
    xs[wave][sr][sc] = xv;

    // X2 per row: wave-parallel butterfly within 16-lane groups.
    float px = xv.x * xv.x + xv.y * xv.y + xv.z * xv.z + xv.w * xv.w;
    px += __shfl_xor(px, 1);
    px += __shfl_xor(px, 2);
    px += __shfl_xor(px, 4);
    px += __shfl_xor(px, 8);
    float x2[TD_RW];
    #pragma unroll
    for (int r = 0; r < TD_RW; ++r) x2[r] = __shfl(px, r * 16);

    __syncthreads();

    const f4* tb = (const f4*)table;         // [64][64] of float4 over k
    f4 acc[TD_RW];
    #pragma unroll
    for (int r = 0; r < TD_RW; ++r) acc[r] = (f4){0.f, 0.f, 0.f, 0.f};
    f4 t2 = {0.f, 0.f, 0.f, 0.f};

    #pragma unroll
    for (int dc = 0; dc < TD_D / 4; ++dc) {
        f4 t0  = tb[(dc * 4 + 0) * 64 + lane];
        f4 t1  = tb[(dc * 4 + 1) * 64 + lane];
        f4 t2v = tb[(dc * 4 + 2) * 64 + lane];
        f4 t3  = tb[(dc * 4 + 3) * 64 + lane];
        t2 += t0 * t0 + t1 * t1 + t2v * t2v + t3 * t3;
        #pragma unroll
        for (int r = 0; r < TD_RW; ++r) {
            f4 xc = xs[wave][r][dc];         // broadcast ds_read_b128
            acc[r] += t0 * xc.x + t1 * xc.y + t2v * xc.z + t3 * xc.w;
        }
    }

    const float s = fabsf(scale[0]);
    #pragma unroll
    for (int r = 0; r < TD_RW; ++r) {
        f4 res = s * (t2 + x2[r] - 2.0f * acc[r]);
        *(f4*)&out[(size_t)(row0 + r) * TD_K + lane * 4] = res;
    }
}

extern "C" void kernel_launch(void* const* d_in, const int* in_sizes, int n_in,
                              void* d_out, int out_size, void* d_ws, size_t ws_size,
                              hipStream_t stream) {
    const float* x     = (const float*)d_in[0];   // [4,2048,64]
    const float* table = (const float*)d_in[1];   // [1,1,64,256]
    const float* scale = (const float*)d_in[2];   // [1,1,1]
    float* out = (float*)d_out;                   // [4,2048,256]

    const int nrows = 4 * 2048;                           // 8192
    const int grid  = nrows / (TD_RW * TD_W);             // 512 blocks
    TableDistance_5669356831001_kernel<<<grid, 256, 0, stream>>>(x, table, scale, out);
}